// Round 2
// baseline (361.820 us; speedup 1.0000x reference)
//
#include <hip/hip_runtime.h>
#include <stdint.h>

#define NB_LAYERS 4
#define KSIZE 5
#define BSZ 8
#define LIN 2048
#define LSEQ 2049
#define CCH 32
#define HCH 16
#define MROWS (BSZ*LSEQ)          // 16392
#define NTILES ((MROWS+15)/16)    // 1025
#define KDIM 576                  // 512 (h*c) + 32 (k3b block) + 32 (skip block)
#define NEG 0.1f
#define BNEPS 1e-5f
#define NBLK 256
#define NTHR 256

typedef _Float16 h2v __attribute__((ext_vector_type(2)));
typedef _Float16 h8v __attribute__((ext_vector_type(8)));
typedef float    f4v __attribute__((ext_vector_type(4)));

union H8 { h8v v; h2v h[4]; };

static __device__ __forceinline__ h2v mkh2(float a, float b) {
  h2v r; r[0] = (_Float16)a; r[1] = (_Float16)b; return r;
}

// grid-wide barrier: monotonic counter, device (agent) scope.
// Safe: grid = 256 blocks <= 256 CUs -> all blocks co-resident.
static __device__ __forceinline__ void gsync(int* cnt, int target) {
  __threadfence();                 // release: make this thread's writes device-visible
  __syncthreads();
  if (threadIdx.x == 0) {
    __hip_atomic_fetch_add(cnt, 1, __ATOMIC_ACQ_REL, __HIP_MEMORY_SCOPE_AGENT);
    while (__hip_atomic_load(cnt, __ATOMIC_RELAXED, __HIP_MEMORY_SCOPE_AGENT) < target) {}
  }
  __syncthreads();
  __threadfence();                 // acquire: invalidate stale L1 lines
}

// ---------------- init: zero BN stats + barrier counter ----------------
__global__ void init_kernel(float* stats, int* cnt) {
  int i = threadIdx.x;
  if (i < NB_LAYERS * 64) stats[i] = 0.f;
  if (i == 0) *cnt = 0;
}

// ---------------- one kernel for the whole network ----------------
__global__ __launch_bounds__(NTHR) void mega_kernel(
    const float* __restrict__ etimes, const int* __restrict__ types,
    const float* __restrict__ emb,
    const float* __restrict__ k1W, const float* __restrict__ k1b,
    const float* __restrict__ k2W, const float* __restrict__ k2b,
    const float* __restrict__ k3W, const float* __restrict__ k3b,
    const float* __restrict__ skipW,
    const float* __restrict__ gamma, const float* __restrict__ beta,
    float* __restrict__ enc_a, float* __restrict__ enc_b,
    _Float16* __restrict__ Wt, float* __restrict__ stats, int* cnt,
    float* __restrict__ out)
{
  const int tid  = threadIdx.x;
  const int gtid = blockIdx.x * NTHR + tid;
  __shared__ float sst[64];
  __shared__ int sm4[4];

  // ===== phase 0: Wt table + embedding + bos rows =====
  for (int id = gtid; id < NB_LAYERS * CCH * KDIM; id += NBLK * NTHR) {
    int layer = id / (CCH * KDIM);
    int rem = id % (CCH * KDIM);
    int n = rem / KDIM;
    int k = rem % KDIM;
    float val;
    if (k < 512)      { int h = k >> 5, c = k & 31; val = k3W[layer*16384 + h*1024 + c*32 + n]; }
    else if (k < 544) { int c = k - 512;            val = k3b[layer*1024 + c*32 + n]; }
    else              { int c = k - 544;            val = skipW[layer*1024 + c*32 + n]; }
    Wt[id] = (_Float16)val;
  }
  for (int id = gtid; id < MROWS * CCH; id += NBLK * NTHR) {
    int row = id >> 5, c = id & 31;
    int b = row / LSEQ, pos = row - b * LSEQ;
    if (pos != 0) {
      int t = types[b * LIN + pos - 1];
      enc_a[id] = (t == 0) ? 0.f : emb[t * CCH + c];
    }
  }
  if (blockIdx.x == 0) {
    int v = 0;
    for (int i = tid; i < BSZ * LIN; i += NTHR) v = max(v, types[i]);
#pragma unroll
    for (int off = 32; off; off >>= 1) v = max(v, __shfl_xor(v, off, 64));
    if ((tid & 63) == 0) sm4[tid >> 6] = v;
    __syncthreads();
    int mx = max(max(sm4[0], sm4[1]), max(sm4[2], sm4[3]));
    int b = tid >> 5, c = tid & 31;           // 256 threads = 8 rows x 32 ch
    enc_a[(b * LSEQ) * CCH + c] = emb[(mx + 1) * CCH + c];
  }

  int bt = NBLK;
  gsync(cnt, bt); bt += NBLK;

  // ===== conv layers =====
  const int lane = tid & 63;
  const int wv   = tid >> 6;
  const int m    = lane & 15;     // A-frag row within tile / B-frag col n
  const int q    = lane >> 4;     // quad: k-subchunk + feat channels q*8..q*8+7
  const int dils[NB_LAYERS] = {1, 2, 4, 8};

#pragma unroll 1
  for (int layer = 0; layer < NB_LAYERS; layer++) {
    const float* enc_in  = (layer & 1) ? enc_b : enc_a;
    float*       enc_out = (layer & 1) ? enc_a : enc_b;
    const int dil = dils[layer];
    const float* k1Wp = k1W + layer * HCH;
    const float* k1bp = k1b + layer * HCH;
    const float* k2Wp = k2W + layer * HCH * HCH;
    const float* k2bp = k2b + layer * HCH;
    const _Float16* Wtl = Wt + layer * CCH * KDIM;
    float* st_out = stats + layer * 64;

    // input transform (BN+lrelu of previous layer) folded into the gather load
    float sc[8], sh[8], slope;
    if (layer > 0) {
      const float* stp = stats + (layer - 1) * 64;
      const float inv = 1.f / (float)MROWS;
      const float* gp = gamma + (layer - 1) * CCH;
      const float* bp = beta + (layer - 1) * CCH;
#pragma unroll
      for (int p = 0; p < 8; p++) {
        int c = q * 8 + p;
        float mu = stp[c] * inv;
        float var = stp[32 + c] * inv - mu * mu;
        float s = gp[c] * rsqrtf(var + BNEPS);
        sc[p] = s; sh[p] = bp[c] - mu * s;
      }
      slope = NEG;
    } else {
#pragma unroll
      for (int p = 0; p < 8; p++) { sc[p] = 1.f; sh[p] = 0.f; }
      slope = 1.f;                 // max(y, y) == y -> identity
    }

    // MLP params (uniform -> scalar regs)
    float k1w[HCH], k1bb[HCH], k2bb[HCH];
#pragma unroll
    for (int h = 0; h < HCH; h++) { k1w[h] = k1Wp[h]; k1bb[h] = k1bp[h]; k2bb[h] = k2bp[h]; }

    const _Float16* wb0 = Wtl + m * KDIM + q * 8;
    const _Float16* wb1 = Wtl + (m + 16) * KDIM + q * 8;

    __syncthreads();
    if (tid < 64) sst[tid] = 0.f;
    __syncthreads();

    for (int tile = blockIdx.x * 4 + wv; tile < NTILES; tile += NBLK * 4) {
      int row = tile * 16 + m;
      bool rvalid = row < MROWS;
      int rowc = min(row, MROWS - 1);
      int b = rowc / LSEQ, pos = rowc % LSEQ;
      float t_l = (pos == 0) ? 0.f : etimes[b * LIN + pos - 1];
      bool mask_l = rvalid && (t_l != 0.f);

      h2v wh[KSIZE][8];     // gm * h2  (fp16 pairs)
      h2v fh[KSIZE][4];     // gathered feats (fp16 pairs)
      h2v fself[4];
      float Fb[8];
#pragma unroll
      for (int jj = 0; jj < 8; jj++) Fb[jj] = 0.f;

#pragma unroll
      for (int tap = 0; tap < KSIZE; tap++) {
        int j = pos - tap * dil;
        int jc = max(j, 0);
        float t_j = (jc == 0) ? 0.f : etimes[b * LIN + jc - 1];
        bool gm = mask_l && (j >= 0) && (t_j != 0.f);
        float dt = gm ? (t_l - t_j) : 0.f;

        const float* fp = enc_in + (b * LSEQ + jc) * CCH + q * 8;
        float4 fA = *(const float4*)(fp);
        float4 fB = *(const float4*)(fp + 4);
        float fv[8] = {fA.x, fA.y, fA.z, fA.w, fB.x, fB.y, fB.z, fB.w};
#pragma unroll
        for (int jj = 0; jj < 8; jj++) {      // BN+lrelu of previous layer
          float x = fmaf(fv[jj], sc[jj], sh[jj]);
          fv[jj] = fmaxf(x, slope * x);
        }

        if (tap == 0) {
          float rv = rvalid ? 1.f : 0.f;
#pragma unroll
          for (int p = 0; p < 4; p++) fself[p] = mkh2(fv[2*p] * rv, fv[2*p+1] * rv);
        }
        float g = gm ? 1.f : 0.f;
#pragma unroll
        for (int jj = 0; jj < 8; jj++) Fb[jj] += g * fv[jj];
#pragma unroll
        for (int p = 0; p < 4; p++) fh[tap][p] = mkh2(fv[2*p], fv[2*p+1]);

        if (__ballot(gm)) {
          float h1[HCH];
#pragma unroll
          for (int h = 0; h < HCH; h++) { float x = fmaf(dt, k1w[h], k1bb[h]); h1[h] = fmaxf(x, NEG * x); }
          float h2[HCH];
#pragma unroll
          for (int h = 0; h < HCH; h++) h2[h] = k2bb[h];
#pragma unroll
          for (int hp = 0; hp < HCH; hp++) {
            float hv = h1[hp];
#pragma unroll
            for (int h = 0; h < HCH; h++) h2[h] = fmaf(hv, k2Wp[hp * HCH + h], h2[h]);
          }
#pragma unroll
          for (int hh = 0; hh < 8; hh++) {
            float a  = h2[2*hh];    a  = fmaxf(a,  NEG * a)  * g;
            float c2 = h2[2*hh+1];  c2 = fmaxf(c2, NEG * c2) * g;
            wh[tap][hh] = mkh2(a, c2);
          }
        } else {
#pragma unroll
          for (int hh = 0; hh < 8; hh++) wh[tap][hh] = mkh2(0.f, 0.f);
        }
      }

      f4v acc0 = {0.f, 0.f, 0.f, 0.f};
      f4v acc1 = {0.f, 0.f, 0.f, 0.f};

#pragma unroll
      for (int ks = 0; ks < 16; ks++) {
        H8 bf0, bf1, af;
        bf0.v = *(const h8v*)(wb0 + ks * 32);
        bf1.v = *(const h8v*)(wb1 + ks * 32);
        h2v u0 = mkh2(0.f,0.f), u1 = mkh2(0.f,0.f), u2 = mkh2(0.f,0.f), u3 = mkh2(0.f,0.f);
#pragma unroll
        for (int tap = 0; tap < KSIZE; tap++) {
          _Float16 w = wh[tap][ks >> 1][ks & 1];
          h2v wd; wd[0] = w; wd[1] = w;
          u0 += wd * fh[tap][0];
          u1 += wd * fh[tap][1];
          u2 += wd * fh[tap][2];
          u3 += wd * fh[tap][3];
        }
        af.h[0] = u0; af.h[1] = u1; af.h[2] = u2; af.h[3] = u3;
        acc0 = __builtin_amdgcn_mfma_f32_16x16x32_f16(af.v, bf0.v, acc0, 0, 0, 0);
        acc1 = __builtin_amdgcn_mfma_f32_16x16x32_f16(af.v, bf1.v, acc1, 0, 0, 0);
      }
      { // k3b block (k = 512..543)
        H8 bf0, bf1, af;
        bf0.v = *(const h8v*)(wb0 + 512);
        bf1.v = *(const h8v*)(wb1 + 512);
#pragma unroll
        for (int p = 0; p < 4; p++) af.h[p] = mkh2(Fb[2*p], Fb[2*p+1]);
        acc0 = __builtin_amdgcn_mfma_f32_16x16x32_f16(af.v, bf0.v, acc0, 0, 0, 0);
        acc1 = __builtin_amdgcn_mfma_f32_16x16x32_f16(af.v, bf1.v, acc1, 0, 0, 0);
      }
      { // skip block (k = 544..575)
        H8 bf0, bf1, af;
        bf0.v = *(const h8v*)(wb0 + 544);
        bf1.v = *(const h8v*)(wb1 + 544);
        af.h[0] = fself[0]; af.h[1] = fself[1]; af.h[2] = fself[2]; af.h[3] = fself[3];
        acc0 = __builtin_amdgcn_mfma_f32_16x16x32_f16(af.v, bf0.v, acc0, 0, 0, 0);
        acc1 = __builtin_amdgcn_mfma_f32_16x16x32_f16(af.v, bf1.v, acc1, 0, 0, 0);
      }

      // epilogue: store raw + BN stats.  D layout: col = lane&15, row = (lane>>4)*4 + r
      float s0 = 0.f, s1 = 0.f, s2 = 0.f, s3 = 0.f;
#pragma unroll
      for (int r = 0; r < 4; r++) {
        float v0 = acc0[r], v1 = acc1[r];
        s0 += v0; s1 += v0 * v0; s2 += v1; s3 += v1 * v1;
        int rd = tile * 16 + q * 4 + r;
        if (rd < MROWS) {
          enc_out[rd * CCH + m] = v0;
          enc_out[rd * CCH + 16 + m] = v1;
        }
      }
      s0 += __shfl_xor(s0, 16, 64); s0 += __shfl_xor(s0, 32, 64);
      s1 += __shfl_xor(s1, 16, 64); s1 += __shfl_xor(s1, 32, 64);
      s2 += __shfl_xor(s2, 16, 64); s2 += __shfl_xor(s2, 32, 64);
      s3 += __shfl_xor(s3, 16, 64); s3 += __shfl_xor(s3, 32, 64);
      if (q == 0) {
        atomicAdd(&sst[m], s0);
        atomicAdd(&sst[32 + m], s1);
        atomicAdd(&sst[16 + m], s2);
        atomicAdd(&sst[48 + m], s3);
      }
    }

    __syncthreads();
    if (tid < 64) atomicAdd(&st_out[tid], sst[tid]);
    gsync(cnt, bt); bt += NBLK;
  }

  // ===== final BN + lrelu -> out  (layer 3 raw landed in enc_a) =====
  {
    const float* stp = stats + 3 * 64;
    const float inv = 1.f / (float)MROWS;
    for (int id = gtid; id < MROWS * CCH; id += NBLK * NTHR) {
      int c = id & 31;
      float mu = stp[c] * inv;
      float var = stp[32 + c] * inv - mu * mu;
      float s = gamma[3 * CCH + c] * rsqrtf(var + BNEPS);
      float v = (enc_a[id] - mu) * s + beta[3 * CCH + c];
      out[id] = fmaxf(v, NEG * v);
    }
  }
}

extern "C" void kernel_launch(void* const* d_in, const int* in_sizes, int n_in,
                              void* d_out, int out_size, void* d_ws, size_t ws_size,
                              hipStream_t stream) {
  (void)in_sizes; (void)n_in; (void)out_size; (void)ws_size;
  const float* event_times = (const float*)d_in[0];
  const int*   event_types = (const int*)d_in[1];
  const float* emb   = (const float*)d_in[2];
  const float* k1W   = (const float*)d_in[3];
  const float* k1b   = (const float*)d_in[4];
  const float* k2W   = (const float*)d_in[5];
  const float* k2b   = (const float*)d_in[6];
  const float* k3W   = (const float*)d_in[7];
  const float* k3b   = (const float*)d_in[8];
  const float* skipW = (const float*)d_in[9];
  // d_in[10] = skipb: BN-invariant, dropped
  const float* gamma = (const float*)d_in[11];
  const float* beta  = (const float*)d_in[12];

  float* enc_a = (float*)d_ws;
  float* enc_b = enc_a + (size_t)MROWS * CCH;
  float* stats = enc_b + (size_t)MROWS * CCH;
  int*   cnt   = (int*)(stats + NB_LAYERS * 64);
  _Float16* Wt = (_Float16*)(((uintptr_t)(cnt + 1) + 255) & ~(uintptr_t)255);

  init_kernel<<<1, 256, 0, stream>>>(stats, cnt);
  mega_kernel<<<NBLK, NTHR, 0, stream>>>(event_times, event_types, emb,
      k1W, k1b, k2W, k2b, k3W, k3b, skipW, gamma, beta,
      enc_a, enc_b, Wt, stats, cnt, (float*)d_out);
}

// Round 3
// 235.519 us; speedup vs baseline: 1.5363x; 1.5363x over previous
//
#include <hip/hip_runtime.h>
#include <stdint.h>

#define NB_LAYERS 4
#define KSIZE 5
#define BSZ 8
#define LIN 2048
#define LSEQ 2049
#define CCH 32
#define HCH 16
#define MROWS (BSZ*LSEQ)          // 16392
#define NTILES ((MROWS+15)/16)    // 1025
#define KDIM 576                  // 512 (h*c) + 32 (k3b block) + 32 (skip block)
#define NEG 0.1f
#define BNEPS 1e-5f
#define NBLK 256
#define NTHR 256

typedef _Float16 h2v __attribute__((ext_vector_type(2)));
typedef _Float16 h8v __attribute__((ext_vector_type(8)));
typedef float    f4v __attribute__((ext_vector_type(4)));

union H8 { h8v v; h2v h[4]; };

static __device__ __forceinline__ h2v mkh2(float a, float b) {
  h2v r; r[0] = (_Float16)a; r[1] = (_Float16)b; return r;
}

// grid-wide barrier: monotonic counter, device (agent) scope.
// Safe: grid = 256 blocks <= 256 CUs -> all blocks co-resident.
// Leader-only fences (syncthreads already drains each wave's vmcnt, so the
// block's stores are in this XCD's L2; one wbl2 publishes them). s_sleep
// backoff keeps the poll traffic off the coherence point so arrival adds
// aren't queued behind a poll flood.
static __device__ __forceinline__ void gsync(int* cnt, int target) {
  __syncthreads();
  if (threadIdx.x == 0) {
    __threadfence();                       // release: L2 writeback (leader only)
    __hip_atomic_fetch_add(cnt, 1, __ATOMIC_RELAXED, __HIP_MEMORY_SCOPE_AGENT);
    while (__hip_atomic_load(cnt, __ATOMIC_RELAXED, __HIP_MEMORY_SCOPE_AGENT) < target)
      __builtin_amdgcn_s_sleep(64);        // ~1.7us per poll
    __threadfence();                       // acquire: invalidate L1/L2
  }
  __syncthreads();
}

// ---------------- init: zero BN stats + barrier counter ----------------
__global__ void init_kernel(float* stats, int* cnt) {
  int i = threadIdx.x;
  if (i < NB_LAYERS * 64) stats[i] = 0.f;
  if (i == 0) *cnt = 0;
}

// ---------------- one kernel for the whole network ----------------
__global__ __launch_bounds__(NTHR) void mega_kernel(
    const float* __restrict__ etimes, const int* __restrict__ types,
    const float* __restrict__ emb,
    const float* __restrict__ k1W, const float* __restrict__ k1b,
    const float* __restrict__ k2W, const float* __restrict__ k2b,
    const float* __restrict__ k3W, const float* __restrict__ k3b,
    const float* __restrict__ skipW,
    const float* __restrict__ gamma, const float* __restrict__ beta,
    float* __restrict__ enc_a, float* __restrict__ enc_b,
    _Float16* __restrict__ Wt, float* __restrict__ stats, int* cnt,
    float* __restrict__ out)
{
  const int tid  = threadIdx.x;
  const int gtid = blockIdx.x * NTHR + tid;
  __shared__ float sst[64];
  __shared__ int sm4[4];

  // ===== phase 0: Wt table + embedding + bos rows =====
  for (int id = gtid; id < NB_LAYERS * CCH * KDIM; id += NBLK * NTHR) {
    int layer = id / (CCH * KDIM);
    int rem = id % (CCH * KDIM);
    int n = rem / KDIM;
    int k = rem % KDIM;
    float val;
    if (k < 512)      { int h = k >> 5, c = k & 31; val = k3W[layer*16384 + h*1024 + c*32 + n]; }
    else if (k < 544) { int c = k - 512;            val = k3b[layer*1024 + c*32 + n]; }
    else              { int c = k - 544;            val = skipW[layer*1024 + c*32 + n]; }
    Wt[id] = (_Float16)val;
  }
  for (int id = gtid; id < MROWS * CCH; id += NBLK * NTHR) {
    int row = id >> 5, c = id & 31;
    int b = row / LSEQ, pos = row - b * LSEQ;
    if (pos != 0) {
      int t = types[b * LIN + pos - 1];
      enc_a[id] = (t == 0) ? 0.f : emb[t * CCH + c];
    }
  }
  if (blockIdx.x == 0) {
    int v = 0;
    for (int i = tid; i < BSZ * LIN; i += NTHR) v = max(v, types[i]);
#pragma unroll
    for (int off = 32; off; off >>= 1) v = max(v, __shfl_xor(v, off, 64));
    if ((tid & 63) == 0) sm4[tid >> 6] = v;
    __syncthreads();
    int mx = max(max(sm4[0], sm4[1]), max(sm4[2], sm4[3]));
    int b = tid >> 5, c = tid & 31;           // 256 threads = 8 rows x 32 ch
    enc_a[(b * LSEQ) * CCH + c] = emb[(mx + 1) * CCH + c];
  }

  int bt = NBLK;
  gsync(cnt, bt); bt += NBLK;

  // ===== conv layers =====
  const int lane = tid & 63;
  const int wv   = tid >> 6;
  const int m    = lane & 15;     // A-frag row within tile / B-frag col n
  const int q    = lane >> 4;     // quad: k-subchunk + feat channels q*8..q*8+7
  const int dils[NB_LAYERS] = {1, 2, 4, 8};

#pragma unroll 1
  for (int layer = 0; layer < NB_LAYERS; layer++) {
    const float* enc_in  = (layer & 1) ? enc_b : enc_a;
    float*       enc_out = (layer & 1) ? enc_a : enc_b;
    const int dil = dils[layer];
    const float* k1Wp = k1W + layer * HCH;
    const float* k1bp = k1b + layer * HCH;
    const float* k2Wp = k2W + layer * HCH * HCH;
    const float* k2bp = k2b + layer * HCH;
    const _Float16* Wtl = Wt + layer * CCH * KDIM;
    float* st_out = stats + layer * 64;

    // input transform (BN+lrelu of previous layer) folded into the gather load
    float sc[8], sh[8], slope;
    if (layer > 0) {
      const float* stp = stats + (layer - 1) * 64;
      const float inv = 1.f / (float)MROWS;
      const float* gp = gamma + (layer - 1) * CCH;
      const float* bp = beta + (layer - 1) * CCH;
#pragma unroll
      for (int p = 0; p < 8; p++) {
        int c = q * 8 + p;
        float mu = stp[c] * inv;
        float var = stp[32 + c] * inv - mu * mu;
        float s = gp[c] * rsqrtf(var + BNEPS);
        sc[p] = s; sh[p] = bp[c] - mu * s;
      }
      slope = NEG;
    } else {
#pragma unroll
      for (int p = 0; p < 8; p++) { sc[p] = 1.f; sh[p] = 0.f; }
      slope = 1.f;                 // max(y, y) == y -> identity
    }

    // MLP params (uniform -> scalar regs)
    float k1w[HCH], k1bb[HCH], k2bb[HCH];
#pragma unroll
    for (int h = 0; h < HCH; h++) { k1w[h] = k1Wp[h]; k1bb[h] = k1bp[h]; k2bb[h] = k2bp[h]; }

    const _Float16* wb0 = Wtl + m * KDIM + q * 8;
    const _Float16* wb1 = Wtl + (m + 16) * KDIM + q * 8;

    __syncthreads();
    if (tid < 64) sst[tid] = 0.f;
    __syncthreads();

    for (int tile = blockIdx.x * 4 + wv; tile < NTILES; tile += NBLK * 4) {
      int row = tile * 16 + m;
      bool rvalid = row < MROWS;
      int rowc = min(row, MROWS - 1);
      int b = rowc / LSEQ, pos = rowc % LSEQ;
      float t_l = (pos == 0) ? 0.f : etimes[b * LIN + pos - 1];
      bool mask_l = rvalid && (t_l != 0.f);

      h2v wh[KSIZE][8];     // gm * h2  (fp16 pairs)
      h2v fh[KSIZE][4];     // gathered feats (fp16 pairs)
      h2v fself[4];
      float Fb[8];
#pragma unroll
      for (int jj = 0; jj < 8; jj++) Fb[jj] = 0.f;

#pragma unroll
      for (int tap = 0; tap < KSIZE; tap++) {
        int j = pos - tap * dil;
        int jc = max(j, 0);
        float t_j = (jc == 0) ? 0.f : etimes[b * LIN + jc - 1];
        bool gm = mask_l && (j >= 0) && (t_j != 0.f);
        float dt = gm ? (t_l - t_j) : 0.f;

        const float* fp = enc_in + (b * LSEQ + jc) * CCH + q * 8;
        float4 fA = *(const float4*)(fp);
        float4 fB = *(const float4*)(fp + 4);
        float fv[8] = {fA.x, fA.y, fA.z, fA.w, fB.x, fB.y, fB.z, fB.w};
#pragma unroll
        for (int jj = 0; jj < 8; jj++) {      // BN+lrelu of previous layer
          float x = fmaf(fv[jj], sc[jj], sh[jj]);
          fv[jj] = fmaxf(x, slope * x);
        }

        if (tap == 0) {
          float rv = rvalid ? 1.f : 0.f;
#pragma unroll
          for (int p = 0; p < 4; p++) fself[p] = mkh2(fv[2*p] * rv, fv[2*p+1] * rv);
        }
        float g = gm ? 1.f : 0.f;
#pragma unroll
        for (int jj = 0; jj < 8; jj++) Fb[jj] += g * fv[jj];
#pragma unroll
        for (int p = 0; p < 4; p++) fh[tap][p] = mkh2(fv[2*p], fv[2*p+1]);

        if (__ballot(gm)) {
          float h1[HCH];
#pragma unroll
          for (int h = 0; h < HCH; h++) { float x = fmaf(dt, k1w[h], k1bb[h]); h1[h] = fmaxf(x, NEG * x); }
          float h2[HCH];
#pragma unroll
          for (int h = 0; h < HCH; h++) h2[h] = k2bb[h];
#pragma unroll
          for (int hp = 0; hp < HCH; hp++) {
            float hv = h1[hp];
#pragma unroll
            for (int h = 0; h < HCH; h++) h2[h] = fmaf(hv, k2Wp[hp * HCH + h], h2[h]);
          }
#pragma unroll
          for (int hh = 0; hh < 8; hh++) {
            float a  = h2[2*hh];    a  = fmaxf(a,  NEG * a)  * g;
            float c2 = h2[2*hh+1];  c2 = fmaxf(c2, NEG * c2) * g;
            wh[tap][hh] = mkh2(a, c2);
          }
        } else {
#pragma unroll
          for (int hh = 0; hh < 8; hh++) wh[tap][hh] = mkh2(0.f, 0.f);
        }
      }

      f4v acc0 = {0.f, 0.f, 0.f, 0.f};
      f4v acc1 = {0.f, 0.f, 0.f, 0.f};

#pragma unroll
      for (int ks = 0; ks < 16; ks++) {
        H8 bf0, bf1, af;
        bf0.v = *(const h8v*)(wb0 + ks * 32);
        bf1.v = *(const h8v*)(wb1 + ks * 32);
        h2v u0 = mkh2(0.f,0.f), u1 = mkh2(0.f,0.f), u2 = mkh2(0.f,0.f), u3 = mkh2(0.f,0.f);
#pragma unroll
        for (int tap = 0; tap < KSIZE; tap++) {
          _Float16 w = wh[tap][ks >> 1][ks & 1];
          h2v wd; wd[0] = w; wd[1] = w;
          u0 += wd * fh[tap][0];
          u1 += wd * fh[tap][1];
          u2 += wd * fh[tap][2];
          u3 += wd * fh[tap][3];
        }
        af.h[0] = u0; af.h[1] = u1; af.h[2] = u2; af.h[3] = u3;
        acc0 = __builtin_amdgcn_mfma_f32_16x16x32_f16(af.v, bf0.v, acc0, 0, 0, 0);
        acc1 = __builtin_amdgcn_mfma_f32_16x16x32_f16(af.v, bf1.v, acc1, 0, 0, 0);
      }
      { // k3b block (k = 512..543)
        H8 bf0, bf1, af;
        bf0.v = *(const h8v*)(wb0 + 512);
        bf1.v = *(const h8v*)(wb1 + 512);
#pragma unroll
        for (int p = 0; p < 4; p++) af.h[p] = mkh2(Fb[2*p], Fb[2*p+1]);
        acc0 = __builtin_amdgcn_mfma_f32_16x16x32_f16(af.v, bf0.v, acc0, 0, 0, 0);
        acc1 = __builtin_amdgcn_mfma_f32_16x16x32_f16(af.v, bf1.v, acc1, 0, 0, 0);
      }
      { // skip block (k = 544..575)
        H8 bf0, bf1, af;
        bf0.v = *(const h8v*)(wb0 + 544);
        bf1.v = *(const h8v*)(wb1 + 544);
        af.h[0] = fself[0]; af.h[1] = fself[1]; af.h[2] = fself[2]; af.h[3] = fself[3];
        acc0 = __builtin_amdgcn_mfma_f32_16x16x32_f16(af.v, bf0.v, acc0, 0, 0, 0);
        acc1 = __builtin_amdgcn_mfma_f32_16x16x32_f16(af.v, bf1.v, acc1, 0, 0, 0);
      }

      // epilogue: store raw + BN stats.  D layout: col = lane&15, row = (lane>>4)*4 + r
      float s0 = 0.f, s1 = 0.f, s2 = 0.f, s3 = 0.f;
#pragma unroll
      for (int r = 0; r < 4; r++) {
        float v0 = acc0[r], v1 = acc1[r];
        s0 += v0; s1 += v0 * v0; s2 += v1; s3 += v1 * v1;
        int rd = tile * 16 + q * 4 + r;
        if (rd < MROWS) {
          enc_out[rd * CCH + m] = v0;
          enc_out[rd * CCH + 16 + m] = v1;
        }
      }
      s0 += __shfl_xor(s0, 16, 64); s0 += __shfl_xor(s0, 32, 64);
      s1 += __shfl_xor(s1, 16, 64); s1 += __shfl_xor(s1, 32, 64);
      s2 += __shfl_xor(s2, 16, 64); s2 += __shfl_xor(s2, 32, 64);
      s3 += __shfl_xor(s3, 16, 64); s3 += __shfl_xor(s3, 32, 64);
      if (q == 0) {
        atomicAdd(&sst[m], s0);
        atomicAdd(&sst[32 + m], s1);
        atomicAdd(&sst[16 + m], s2);
        atomicAdd(&sst[48 + m], s3);
      }
    }

    __syncthreads();
    if (tid < 64) atomicAdd(&st_out[tid], sst[tid]);
    gsync(cnt, bt); bt += NBLK;
  }

  // ===== final BN + lrelu -> out  (layer 3 raw landed in enc_a) =====
  {
    const float* stp = stats + 3 * 64;
    const float inv = 1.f / (float)MROWS;
    for (int id = gtid; id < MROWS * CCH; id += NBLK * NTHR) {
      int c = id & 31;
      float mu = stp[c] * inv;
      float var = stp[32 + c] * inv - mu * mu;
      float s = gamma[3 * CCH + c] * rsqrtf(var + BNEPS);
      float v = (enc_a[id] - mu) * s + beta[3 * CCH + c];
      out[id] = fmaxf(v, NEG * v);
    }
  }
}

extern "C" void kernel_launch(void* const* d_in, const int* in_sizes, int n_in,
                              void* d_out, int out_size, void* d_ws, size_t ws_size,
                              hipStream_t stream) {
  (void)in_sizes; (void)n_in; (void)out_size; (void)ws_size;
  const float* event_times = (const float*)d_in[0];
  const int*   event_types = (const int*)d_in[1];
  const float* emb   = (const float*)d_in[2];
  const float* k1W   = (const float*)d_in[3];
  const float* k1b   = (const float*)d_in[4];
  const float* k2W   = (const float*)d_in[5];
  const float* k2b   = (const float*)d_in[6];
  const float* k3W   = (const float*)d_in[7];
  const float* k3b   = (const float*)d_in[8];
  const float* skipW = (const float*)d_in[9];
  // d_in[10] = skipb: BN-invariant, dropped
  const float* gamma = (const float*)d_in[11];
  const float* beta  = (const float*)d_in[12];

  float* enc_a = (float*)d_ws;
  float* enc_b = enc_a + (size_t)MROWS * CCH;
  float* stats = enc_b + (size_t)MROWS * CCH;
  int*   cnt   = (int*)(stats + NB_LAYERS * 64);
  _Float16* Wt = (_Float16*)(((uintptr_t)(cnt + 1) + 255) & ~(uintptr_t)255);

  init_kernel<<<1, 256, 0, stream>>>(stats, cnt);
  mega_kernel<<<NBLK, NTHR, 0, stream>>>(event_times, event_types, emb,
      k1W, k1b, k2W, k2b, k3W, k3b, skipW, gamma, beta,
      enc_a, enc_b, Wt, stats, cnt, (float*)d_out);
}

// Round 4
// 207.042 us; speedup vs baseline: 1.7476x; 1.1375x over previous
//
#include <hip/hip_runtime.h>
#include <stdint.h>

#define NB_LAYERS 4
#define KSIZE 5
#define BSZ 8
#define LIN 2048
#define LSEQ 2049
#define CCH 32
#define HCH 16
#define MROWS (BSZ*LSEQ)          // 16392
#define NTILES ((MROWS+15)/16)    // 1025
#define KDIM 576                  // 512 (h*c) + 32 (k3b block) + 32 (skip block)
#define NEG 0.1f
#define BNEPS 1e-5f
#define NBLK 256
#define NTHR 256
#define SLOTP 32                  // 128B pad per arrival slot (ints)

typedef _Float16 h2v __attribute__((ext_vector_type(2)));
typedef _Float16 h8v __attribute__((ext_vector_type(8)));
typedef float    f4v __attribute__((ext_vector_type(4)));

union H8 { h8v v; h2v h[4]; };

static __device__ __forceinline__ h2v mkh2(float a, float b) {
  h2v r; r[0] = (_Float16)a; r[1] = (_Float16)b; return r;
}

// Grid barrier, zero contended RMWs. Blocks 1..255 exchange `epoch` into their
// own 128B-padded slot (parallel at coherence point); block 0's wave 0 sweeps
// all slots (4 relaxed agent loads/lane), then exchanges `epoch` into the
// release flag; waiters poll it with short s_sleep. Poison (0xAA.. = negative)
// is a valid "not arrived"/"not released" state -> no init pass needed, epochs
// are monotonic 1..5 within one call.
// Co-residency: 256 blocks <= 256 CUs, guaranteed resident.
static __device__ __forceinline__ void gsync(int* arrive, int* release, int epoch) {
  __syncthreads();
  if (blockIdx.x == 0) {
    const int ln = threadIdx.x;
    if (ln == 0) __threadfence();          // release block 0's data
    if (ln < 64) {
      for (;;) {
        bool ok = true;
#pragma unroll
        for (int i = 0; i < 4; i++) {
          int b = ln * 4 + i;
          if (b != 0)
            ok = ok && (__hip_atomic_load(arrive + b * SLOTP, __ATOMIC_RELAXED,
                                          __HIP_MEMORY_SCOPE_AGENT) >= epoch);
        }
        if (__all(ok)) break;
        __builtin_amdgcn_s_sleep(2);       // ~0.05us
      }
      if (ln == 0) {
        __threadfence();                   // acquire for block 0 + order release
        __hip_atomic_exchange(release, epoch, __ATOMIC_RELAXED, __HIP_MEMORY_SCOPE_AGENT);
      }
    }
  } else {
    if (threadIdx.x == 0) {
      __threadfence();                     // release: publish this block's data
      __hip_atomic_exchange(arrive + blockIdx.x * SLOTP, epoch,
                            __ATOMIC_RELAXED, __HIP_MEMORY_SCOPE_AGENT);
      while (__hip_atomic_load(release, __ATOMIC_RELAXED, __HIP_MEMORY_SCOPE_AGENT) < epoch)
        __builtin_amdgcn_s_sleep(8);       // ~0.21us
      __threadfence();                     // acquire: drop stale L1/L2 lines
    }
  }
  __syncthreads();
}

// ---------------- one kernel for the whole network ----------------
__global__ __launch_bounds__(NTHR) void mega_kernel(
    const float* __restrict__ etimes, const int* __restrict__ types,
    const float* __restrict__ emb,
    const float* __restrict__ k1W, const float* __restrict__ k1b,
    const float* __restrict__ k2W, const float* __restrict__ k2b,
    const float* __restrict__ k3W, const float* __restrict__ k3b,
    const float* __restrict__ skipW,
    const float* __restrict__ gamma, const float* __restrict__ beta,
    float* __restrict__ enc_a, float* __restrict__ enc_b,
    _Float16* __restrict__ Wt, float* __restrict__ stats,
    int* arrive, int* release,
    float* __restrict__ out)
{
  const int tid  = threadIdx.x;
  const int gtid = blockIdx.x * NTHR + tid;
  __shared__ float sst[64];
  __shared__ int sm4[4];

  // ===== phase 0: stats zero + Wt table + embedding + bos rows =====
  if (gtid < NB_LAYERS * 64) stats[gtid] = 0.f;
  for (int id = gtid; id < NB_LAYERS * CCH * KDIM; id += NBLK * NTHR) {
    int layer = id / (CCH * KDIM);
    int rem = id % (CCH * KDIM);
    int n = rem / KDIM;
    int k = rem % KDIM;
    float val;
    if (k < 512)      { int h = k >> 5, c = k & 31; val = k3W[layer*16384 + h*1024 + c*32 + n]; }
    else if (k < 544) { int c = k - 512;            val = k3b[layer*1024 + c*32 + n]; }
    else              { int c = k - 544;            val = skipW[layer*1024 + c*32 + n]; }
    Wt[id] = (_Float16)val;
  }
  for (int id = gtid; id < MROWS * CCH; id += NBLK * NTHR) {
    int row = id >> 5, c = id & 31;
    int b = row / LSEQ, pos = row - b * LSEQ;
    if (pos != 0) {
      int t = types[b * LIN + pos - 1];
      enc_a[id] = (t == 0) ? 0.f : emb[t * CCH + c];
    }
  }
  if (blockIdx.x == 0) {
    int v = 0;
    for (int i = tid; i < BSZ * LIN; i += NTHR) v = max(v, types[i]);
#pragma unroll
    for (int off = 32; off; off >>= 1) v = max(v, __shfl_xor(v, off, 64));
    if ((tid & 63) == 0) sm4[tid >> 6] = v;
    __syncthreads();
    int mx = max(max(sm4[0], sm4[1]), max(sm4[2], sm4[3]));
    int b = tid >> 5, c = tid & 31;           // 256 threads = 8 rows x 32 ch
    enc_a[(b * LSEQ) * CCH + c] = emb[(mx + 1) * CCH + c];
  }

  gsync(arrive, release, 1);

  // ===== conv layers =====
  const int lane = tid & 63;
  const int wv   = tid >> 6;
  const int m    = lane & 15;     // A-frag row within tile / B-frag col n
  const int q    = lane >> 4;     // quad: k-subchunk + feat channels q*8..q*8+7
  const int dils[NB_LAYERS] = {1, 2, 4, 8};

#pragma unroll 1
  for (int layer = 0; layer < NB_LAYERS; layer++) {
    const float* enc_in  = (layer & 1) ? enc_b : enc_a;
    float*       enc_out = (layer & 1) ? enc_a : enc_b;
    const int dil = dils[layer];
    const float* k1Wp = k1W + layer * HCH;
    const float* k1bp = k1b + layer * HCH;
    const float* k2Wp = k2W + layer * HCH * HCH;
    const float* k2bp = k2b + layer * HCH;
    const _Float16* Wtl = Wt + layer * CCH * KDIM;
    float* st_out = stats + layer * 64;

    // input transform (BN+lrelu of previous layer) folded into the gather load
    float sc[8], sh[8], slope;
    if (layer > 0) {
      const float* stp = stats + (layer - 1) * 64;
      const float inv = 1.f / (float)MROWS;
      const float* gp = gamma + (layer - 1) * CCH;
      const float* bp = beta + (layer - 1) * CCH;
#pragma unroll
      for (int p = 0; p < 8; p++) {
        int c = q * 8 + p;
        float mu = stp[c] * inv;
        float var = stp[32 + c] * inv - mu * mu;
        float s = gp[c] * rsqrtf(var + BNEPS);
        sc[p] = s; sh[p] = bp[c] - mu * s;
      }
      slope = NEG;
    } else {
#pragma unroll
      for (int p = 0; p < 8; p++) { sc[p] = 1.f; sh[p] = 0.f; }
      slope = 1.f;                 // max(y, y) == y -> identity
    }

    // MLP params (uniform -> scalar regs)
    float k1w[HCH], k1bb[HCH], k2bb[HCH];
#pragma unroll
    for (int h = 0; h < HCH; h++) { k1w[h] = k1Wp[h]; k1bb[h] = k1bp[h]; k2bb[h] = k2bp[h]; }

    const _Float16* wb0 = Wtl + m * KDIM + q * 8;
    const _Float16* wb1 = Wtl + (m + 16) * KDIM + q * 8;

    __syncthreads();
    if (tid < 64) sst[tid] = 0.f;
    __syncthreads();

    for (int tile = blockIdx.x * 4 + wv; tile < NTILES; tile += NBLK * 4) {
      int row = tile * 16 + m;
      bool rvalid = row < MROWS;
      int rowc = min(row, MROWS - 1);
      int b = rowc / LSEQ, pos = rowc % LSEQ;
      float t_l = (pos == 0) ? 0.f : etimes[b * LIN + pos - 1];
      bool mask_l = rvalid && (t_l != 0.f);

      h2v wh[KSIZE][8];     // gm * h2  (fp16 pairs)
      h2v fh[KSIZE][4];     // gathered feats (fp16 pairs)
      h2v fself[4];
      float Fb[8];
#pragma unroll
      for (int jj = 0; jj < 8; jj++) Fb[jj] = 0.f;

#pragma unroll
      for (int tap = 0; tap < KSIZE; tap++) {
        int j = pos - tap * dil;
        int jc = max(j, 0);
        float t_j = (jc == 0) ? 0.f : etimes[b * LIN + jc - 1];
        bool gm = mask_l && (j >= 0) && (t_j != 0.f);
        float dt = gm ? (t_l - t_j) : 0.f;

        const float* fp = enc_in + (b * LSEQ + jc) * CCH + q * 8;
        float4 fA = *(const float4*)(fp);
        float4 fB = *(const float4*)(fp + 4);
        float fv[8] = {fA.x, fA.y, fA.z, fA.w, fB.x, fB.y, fB.z, fB.w};
#pragma unroll
        for (int jj = 0; jj < 8; jj++) {      // BN+lrelu of previous layer
          float x = fmaf(fv[jj], sc[jj], sh[jj]);
          fv[jj] = fmaxf(x, slope * x);
        }

        if (tap == 0) {
          float rv = rvalid ? 1.f : 0.f;
#pragma unroll
          for (int p = 0; p < 4; p++) fself[p] = mkh2(fv[2*p] * rv, fv[2*p+1] * rv);
        }
        float g = gm ? 1.f : 0.f;
#pragma unroll
        for (int jj = 0; jj < 8; jj++) Fb[jj] += g * fv[jj];
#pragma unroll
        for (int p = 0; p < 4; p++) fh[tap][p] = mkh2(fv[2*p], fv[2*p+1]);

        if (__ballot(gm)) {
          float h1[HCH];
#pragma unroll
          for (int h = 0; h < HCH; h++) { float x = fmaf(dt, k1w[h], k1bb[h]); h1[h] = fmaxf(x, NEG * x); }
          float h2[HCH];
#pragma unroll
          for (int h = 0; h < HCH; h++) h2[h] = k2bb[h];
#pragma unroll
          for (int hp = 0; hp < HCH; hp++) {
            float hv = h1[hp];
#pragma unroll
            for (int h = 0; h < HCH; h++) h2[h] = fmaf(hv, k2Wp[hp * HCH + h], h2[h]);
          }
#pragma unroll
          for (int hh = 0; hh < 8; hh++) {
            float a  = h2[2*hh];    a  = fmaxf(a,  NEG * a)  * g;
            float c2 = h2[2*hh+1];  c2 = fmaxf(c2, NEG * c2) * g;
            wh[tap][hh] = mkh2(a, c2);
          }
        } else {
#pragma unroll
          for (int hh = 0; hh < 8; hh++) wh[tap][hh] = mkh2(0.f, 0.f);
        }
      }

      f4v acc0 = {0.f, 0.f, 0.f, 0.f};
      f4v acc1 = {0.f, 0.f, 0.f, 0.f};

#pragma unroll
      for (int ks = 0; ks < 16; ks++) {
        H8 bf0, bf1, af;
        bf0.v = *(const h8v*)(wb0 + ks * 32);
        bf1.v = *(const h8v*)(wb1 + ks * 32);
        h2v u0 = mkh2(0.f,0.f), u1 = mkh2(0.f,0.f), u2 = mkh2(0.f,0.f), u3 = mkh2(0.f,0.f);
#pragma unroll
        for (int tap = 0; tap < KSIZE; tap++) {
          _Float16 w = wh[tap][ks >> 1][ks & 1];
          h2v wd; wd[0] = w; wd[1] = w;
          u0 += wd * fh[tap][0];
          u1 += wd * fh[tap][1];
          u2 += wd * fh[tap][2];
          u3 += wd * fh[tap][3];
        }
        af.h[0] = u0; af.h[1] = u1; af.h[2] = u2; af.h[3] = u3;
        acc0 = __builtin_amdgcn_mfma_f32_16x16x32_f16(af.v, bf0.v, acc0, 0, 0, 0);
        acc1 = __builtin_amdgcn_mfma_f32_16x16x32_f16(af.v, bf1.v, acc1, 0, 0, 0);
      }
      { // k3b block (k = 512..543)
        H8 bf0, bf1, af;
        bf0.v = *(const h8v*)(wb0 + 512);
        bf1.v = *(const h8v*)(wb1 + 512);
#pragma unroll
        for (int p = 0; p < 4; p++) af.h[p] = mkh2(Fb[2*p], Fb[2*p+1]);
        acc0 = __builtin_amdgcn_mfma_f32_16x16x32_f16(af.v, bf0.v, acc0, 0, 0, 0);
        acc1 = __builtin_amdgcn_mfma_f32_16x16x32_f16(af.v, bf1.v, acc1, 0, 0, 0);
      }
      { // skip block (k = 544..575)
        H8 bf0, bf1, af;
        bf0.v = *(const h8v*)(wb0 + 544);
        bf1.v = *(const h8v*)(wb1 + 544);
        af.h[0] = fself[0]; af.h[1] = fself[1]; af.h[2] = fself[2]; af.h[3] = fself[3];
        acc0 = __builtin_amdgcn_mfma_f32_16x16x32_f16(af.v, bf0.v, acc0, 0, 0, 0);
        acc1 = __builtin_amdgcn_mfma_f32_16x16x32_f16(af.v, bf1.v, acc1, 0, 0, 0);
      }

      // epilogue: store raw + BN stats.  D layout: col = lane&15, row = (lane>>4)*4 + r
      float s0 = 0.f, s1 = 0.f, s2 = 0.f, s3 = 0.f;
#pragma unroll
      for (int r = 0; r < 4; r++) {
        float v0 = acc0[r], v1 = acc1[r];
        s0 += v0; s1 += v0 * v0; s2 += v1; s3 += v1 * v1;
        int rd = tile * 16 + q * 4 + r;
        if (rd < MROWS) {
          enc_out[rd * CCH + m] = v0;
          enc_out[rd * CCH + 16 + m] = v1;
        }
      }
      s0 += __shfl_xor(s0, 16, 64); s0 += __shfl_xor(s0, 32, 64);
      s1 += __shfl_xor(s1, 16, 64); s1 += __shfl_xor(s1, 32, 64);
      s2 += __shfl_xor(s2, 16, 64); s2 += __shfl_xor(s2, 32, 64);
      s3 += __shfl_xor(s3, 16, 64); s3 += __shfl_xor(s3, 32, 64);
      if (q == 0) {
        atomicAdd(&sst[m], s0);
        atomicAdd(&sst[32 + m], s1);
        atomicAdd(&sst[16 + m], s2);
        atomicAdd(&sst[48 + m], s3);
      }
    }

    __syncthreads();
    if (tid < 64) atomicAdd(&st_out[tid], sst[tid]);
    gsync(arrive, release, 2 + layer);
  }

  // ===== final BN + lrelu -> out  (layer 3 raw landed in enc_a) =====
  {
    const float* stp = stats + 3 * 64;
    const float inv = 1.f / (float)MROWS;
    for (int id = gtid; id < MROWS * CCH; id += NBLK * NTHR) {
      int c = id & 31;
      float mu = stp[c] * inv;
      float var = stp[32 + c] * inv - mu * mu;
      float s = gamma[3 * CCH + c] * rsqrtf(var + BNEPS);
      float v = (enc_a[id] - mu) * s + beta[3 * CCH + c];
      out[id] = fmaxf(v, NEG * v);
    }
  }
}

extern "C" void kernel_launch(void* const* d_in, const int* in_sizes, int n_in,
                              void* d_out, int out_size, void* d_ws, size_t ws_size,
                              hipStream_t stream) {
  (void)in_sizes; (void)n_in; (void)out_size; (void)ws_size;
  const float* event_times = (const float*)d_in[0];
  const int*   event_types = (const int*)d_in[1];
  const float* emb   = (const float*)d_in[2];
  const float* k1W   = (const float*)d_in[3];
  const float* k1b   = (const float*)d_in[4];
  const float* k2W   = (const float*)d_in[5];
  const float* k2b   = (const float*)d_in[6];
  const float* k3W   = (const float*)d_in[7];
  const float* k3b   = (const float*)d_in[8];
  const float* skipW = (const float*)d_in[9];
  // d_in[10] = skipb: BN-invariant, dropped
  const float* gamma = (const float*)d_in[11];
  const float* beta  = (const float*)d_in[12];

  float* enc_a = (float*)d_ws;
  float* enc_b = enc_a + (size_t)MROWS * CCH;
  float* stats = enc_b + (size_t)MROWS * CCH;
  int*   arrive  = (int*)(((uintptr_t)(stats + NB_LAYERS * 64) + 127) & ~(uintptr_t)127);
  int*   release = arrive + NBLK * SLOTP;
  _Float16* Wt = (_Float16*)(((uintptr_t)(release + SLOTP) + 255) & ~(uintptr_t)255);

  mega_kernel<<<NBLK, NTHR, 0, stream>>>(event_times, event_types, emb,
      k1W, k1b, k2W, k2b, k3W, k3b, skipW, gamma, beta,
      enc_a, enc_b, Wt, stats, arrive, release, (float*)d_out);
}